// Round 1
// baseline (27.629 us; speedup 1.0000x reference)
//
#include <hip/hip_runtime.h>

// Problem constants (fixed by the reference)
#define BB   4096
#define NN   16
#define AA   8
#define DIN  128
#define H1C  64
#define DPC  64
#define DZC  64

// One wave (64 threads) per env. The whole reference collapses to:
//   agg   = mean_n obs[b,n,:]                        [128]
//   h     = relu(agg @ W1 + b1)                      [64]
//   p     = h @ W2 + b2                              [64]  (obs_proc1)
//   z     = p @ Wfc                                  [64]
//   e     = leaky_relu(z . (Wattn[:64]+Wattn[64:]))  scalar
//   w_b   = sigmoid(e)                               scalar (the entire w output!)
//   c     = p . Wv[:64] + bv                         scalar
//   dv[j] = (pi[b,j]-act[b,j]) . Wv[64:72]           [16]
//   Sv    = sum(pi.v) - w_b * sum((pi-act).v)        scalar
//   x[b,d,j] = c + (Sv + w_b*dv[j]) / 16             (independent of d!)
__global__ __launch_bounds__(64)
void critic_kernel(const float* __restrict__ obs,      // [B*N, 128]
                   const float* __restrict__ policies, // [B*N, 8]
                   const float* __restrict__ actions,  // [B*N, 8]
                   const float* __restrict__ W1,       // [128,64]
                   const float* __restrict__ b1,       // [64]
                   const float* __restrict__ W2,       // [64,64]
                   const float* __restrict__ b2,       // [64]
                   const float* __restrict__ Wfc,      // [64,64]
                   const float* __restrict__ Wattn,    // [128]
                   const float* __restrict__ Wv,       // [72]
                   const float* __restrict__ bv,       // [1]
                   float* __restrict__ out_x,          // [B*N*N]
                   float* __restrict__ out_w)          // [B*N*N]
{
    const int b = blockIdx.x;
    const int l = threadIdx.x;

    __shared__ float s_agg[DIN];
    __shared__ float s_h[H1C];
    __shared__ float s_p[DPC];
    __shared__ float s_dv[16];

    // ---- 1. column means of the 16x128 obs tile (vectorized float4 loads) ----
    // flat float index of lane l, iter t: (t*64+l)*4 = 256t + 4l
    //   column = (4l) mod 128 (constant over t), rows covered: l<32 -> even, l>=32 -> odd
    const float4* obs4 = reinterpret_cast<const float4*>(obs + (size_t)b * NN * DIN);
    float4 acc = make_float4(0.f, 0.f, 0.f, 0.f);
    #pragma unroll
    for (int t = 0; t < 8; ++t) {
        float4 v = obs4[t * 64 + l];
        acc.x += v.x; acc.y += v.y; acc.z += v.z; acc.w += v.w;
    }
    acc.x += __shfl_xor(acc.x, 32);
    acc.y += __shfl_xor(acc.y, 32);
    acc.z += __shfl_xor(acc.z, 32);
    acc.w += __shfl_xor(acc.w, 32);
    if (l < 32) {
        const float inv = 1.0f / 16.0f;
        reinterpret_cast<float4*>(s_agg)[l] =
            make_float4(acc.x * inv, acc.y * inv, acc.z * inv, acc.w * inv);
    }
    __syncthreads();

    // ---- 2. h = relu(agg @ W1 + b1) : lane l owns output column l ----
    float hacc = b1[l];
    #pragma unroll 4
    for (int d = 0; d < DIN; ++d)
        hacc = fmaf(s_agg[d], W1[d * H1C + l], hacc);
    s_h[l] = fmaxf(hacc, 0.0f);
    __syncthreads();

    // ---- 3. p = h @ W2 + b2 ----
    float pacc = b2[l];
    #pragma unroll 4
    for (int k = 0; k < H1C; ++k)
        pacc = fmaf(s_h[k], W2[k * DPC + l], pacc);
    s_p[l] = pacc;
    __syncthreads();

    // ---- 4. z = p @ Wfc ; attention scalar + value-head bias scalar ----
    float zacc = 0.0f;
    #pragma unroll 4
    for (int k = 0; k < DPC; ++k)
        zacc = fmaf(s_p[k], Wfc[k * DZC + l], zacc);

    float t0 = zacc * (Wattn[l] + Wattn[DZC + l]);  // -> e = leaky(sum)
    float t1 = s_p[l] * Wv[l];                      // -> c  = sum + bv
    #pragma unroll
    for (int m = 32; m >= 1; m >>= 1) {
        t0 += __shfl_xor(t0, m);
        t1 += __shfl_xor(t1, m);
    }
    const float e   = (t0 > 0.0f) ? t0 : 0.01f * t0;   // jax leaky_relu slope 0.01
    const float wgt = 1.0f / (1.0f + expf(-e));
    const float c   = t1 + bv[0];

    // ---- 5. policies / actions dot products ----
    // per env: 128 floats each; lane l holds (j=l>>3, a=l&7) and (j=8+(l>>3), a=l&7)
    const float* Pb = policies + (size_t)b * (NN * AA);
    const float* Ab = actions  + (size_t)b * (NN * AA);
    const float pv0 = Pb[l], pv1 = Pb[64 + l];
    const float av0 = Ab[l], av1 = Ab[64 + l];
    const float va  = Wv[64 + (l & 7)];

    float q0 = (pv0 - av0) * va;          // contributes to dv[l>>3]
    float q1 = (pv1 - av1) * va;          // contributes to dv[8+(l>>3)]
    float fq = q0 + q1;                   // full sum of (pi-act).v
    float fp = (pv0 + pv1) * va;          // full sum of pi.v

    #pragma unroll
    for (int m = 1; m <= 4; m <<= 1) {    // segmented 8-lane reduce (over a)
        q0 += __shfl_xor(q0, m);
        q1 += __shfl_xor(q1, m);
    }
    #pragma unroll
    for (int m = 32; m >= 1; m >>= 1) {   // full-wave reduces
        fq += __shfl_xor(fq, m);
        fp += __shfl_xor(fp, m);
    }
    const float Sv = fp - wgt * fq;       // w*sumAv + (1-w)*sumPv

    if ((l & 7) == 0) {
        s_dv[l >> 3]     = q0;
        s_dv[8 + (l >> 3)] = q1;
    }
    __syncthreads();

    // ---- 6. outputs: 256 x-values (16 distinct, broadcast over d) + scalar w ----
    const float invN = 1.0f / 16.0f;
    const int j0 = (4 * l) & 15;          // j0 in {0,4,8,12}; j0..j0+3 never wrap
    float4 xo, wo;
    xo.x = fmaf(wgt, s_dv[j0 + 0], Sv) * invN + c;
    xo.y = fmaf(wgt, s_dv[j0 + 1], Sv) * invN + c;
    xo.z = fmaf(wgt, s_dv[j0 + 2], Sv) * invN + c;
    xo.w = fmaf(wgt, s_dv[j0 + 3], Sv) * invN + c;
    wo.x = wo.y = wo.z = wo.w = wgt;

    const size_t base = (size_t)b * (NN * NN) + 4 * l;
    *reinterpret_cast<float4*>(out_x + base) = xo;
    *reinterpret_cast<float4*>(out_w + base) = wo;
}

extern "C" void kernel_launch(void* const* d_in, const int* in_sizes, int n_in,
                              void* d_out, int out_size, void* d_ws, size_t ws_size,
                              hipStream_t stream) {
    const float* obs      = (const float*)d_in[0];
    const float* policies = (const float*)d_in[1];
    const float* actions  = (const float*)d_in[2];
    const float* W1       = (const float*)d_in[3];
    const float* b1       = (const float*)d_in[4];
    const float* W2       = (const float*)d_in[5];
    const float* b2       = (const float*)d_in[6];
    const float* Wfc      = (const float*)d_in[7];
    const float* Wattn    = (const float*)d_in[8];
    const float* Wv       = (const float*)d_in[9];
    const float* bv       = (const float*)d_in[10];

    float* out_x = (float*)d_out;                       // [B*N*N] = 1048576
    float* out_w = out_x + (size_t)BB * NN * NN;        // second tuple element

    critic_kernel<<<BB, 64, 0, stream>>>(obs, policies, actions,
                                         W1, b1, W2, b2, Wfc, Wattn, Wv, bv,
                                         out_x, out_w);
}

// Round 3
// 20.999 us; speedup vs baseline: 1.3158x; 1.3158x over previous
//
#include <hip/hip_runtime.h>

// Problem constants (fixed by the reference)
#define BB   4096
#define NN   16
#define AA   8
#define DIN  128
#define H1C  64
#define DPC  64
#define DZC  64

#define GENV 8     // envs per block
#define WENV 4     // envs per wave (ILP factor)
#define NTHR 128   // 2 waves per block

// Collapsed reference (round-0 derivation, verified passing in round 1):
//   agg   = mean_n obs[b,n,:]                      [128]
//   h     = relu(agg @ W1 + b1)                    [64]
//   p     = h @ W2 + b2                            [64]
//   z     = p @ Wfc                                [64]
//   wgt   = sigmoid(leaky_relu(z . (Wa[:64]+Wa[64:])))  scalar -> entire w output
//   c     = p . Wv[:64] + bv                       scalar
//   dv[j] = (pi[b,j]-act[b,j]) . Wv[64:72]         [16]
//   Sv    = sum(pi.v) - wgt * sum((pi-act).v)
//   x[b,d,j] = c + (Sv + wgt*dv[j]) / 16           (independent of d)
__global__ __launch_bounds__(NTHR, 1)
void critic_kernel(const float* __restrict__ obs,      // [B*N, 128]
                   const float* __restrict__ policies, // [B*N, 8]
                   const float* __restrict__ actions,  // [B*N, 8]
                   const float* __restrict__ W1,       // [128,64]
                   const float* __restrict__ b1,       // [64]
                   const float* __restrict__ W2,       // [64,64]
                   const float* __restrict__ b2,       // [64]
                   const float* __restrict__ Wfc,      // [64,64]
                   const float* __restrict__ Wattn,    // [128]
                   const float* __restrict__ Wv,       // [72]
                   const float* __restrict__ bv,       // [1]
                   float* __restrict__ out_x,          // [B*N*N]
                   float* __restrict__ out_w)          // [B*N*N]
{
    __shared__ float sW1[DIN * H1C];   // 32 KB
    __shared__ float sW2[H1C * DPC];   // 16 KB
    __shared__ float sWfc[DPC * DZC];  // 16 KB
    __shared__ float sAgg[GENV][DIN];  // 4 KB
    __shared__ float sH[GENV][H1C];    // 2 KB
    __shared__ float sP[GENV][DPC];    // 2 KB
    __shared__ float sDv[GENV][16];    // 0.5 KB

    const int tid = threadIdx.x;
    const int l   = tid & 63;
    const int wv  = tid >> 6;
    const int le0 = wv * WENV;                       // local env base of this wave
    const int e0  = blockIdx.x * GENV + le0;         // global env base of this wave

    // ---- hoisted small params ----
    const float b1v = b1[l];
    const float b2v = b2[l];
    const float wa0 = Wattn[l];
    const float wa1 = Wattn[DZC + l];
    const float wvv = Wv[l];
    const float va  = Wv[64 + (l & 7)];
    const float bvv = bv[0];

    // ---- stage weights into LDS (cooperative) ----
    {
        const float4* g1 = reinterpret_cast<const float4*>(W1);
        float4*       s1 = reinterpret_cast<float4*>(sW1);
        #pragma unroll
        for (int i = 0; i < (DIN * H1C / 4) / NTHR; ++i)
            s1[i * NTHR + tid] = g1[i * NTHR + tid];
        const float4* g2 = reinterpret_cast<const float4*>(W2);
        float4*       s2 = reinterpret_cast<float4*>(sW2);
        #pragma unroll
        for (int i = 0; i < (H1C * DPC / 4) / NTHR; ++i)
            s2[i * NTHR + tid] = g2[i * NTHR + tid];
        const float4* g3 = reinterpret_cast<const float4*>(Wfc);
        float4*       s3 = reinterpret_cast<float4*>(sWfc);
        #pragma unroll
        for (int i = 0; i < (DPC * DZC / 4) / NTHR; ++i)
            s3[i * NTHR + tid] = g3[i * NTHR + tid];
    }

    // ---- obs means per env (round-1 order: per-lane sum of 8, xor-32 pair) ----
    #pragma unroll
    for (int ee = 0; ee < WENV; ++ee) {
        const float4* o4 = reinterpret_cast<const float4*>(obs + (size_t)(e0 + ee) * NN * DIN);
        float4 a = make_float4(0.f, 0.f, 0.f, 0.f);
        #pragma unroll
        for (int t = 0; t < 8; ++t) {
            const float4 v = o4[t * 64 + l];
            a.x += v.x; a.y += v.y; a.z += v.z; a.w += v.w;
        }
        a.x += __shfl_xor(a.x, 32);
        a.y += __shfl_xor(a.y, 32);
        a.z += __shfl_xor(a.z, 32);
        a.w += __shfl_xor(a.w, 32);
        if (l < 32) {
            const float inv = 1.0f / 16.0f;
            reinterpret_cast<float4*>(sAgg[le0 + ee])[l] =
                make_float4(a.x * inv, a.y * inv, a.z * inv, a.w * inv);
        }
    }

    // ---- policies/actions loads (early issue) ----
    float pv0[WENV], pv1[WENV], av0[WENV], av1[WENV];
    #pragma unroll
    for (int ee = 0; ee < WENV; ++ee) {
        const float* Pb = policies + (size_t)(e0 + ee) * (NN * AA);
        const float* Ab = actions  + (size_t)(e0 + ee) * (NN * AA);
        pv0[ee] = Pb[l]; pv1[ee] = Pb[64 + l];
        av0[ee] = Ab[l]; av1[ee] = Ab[64 + l];
    }

    __syncthreads();   // weights + sAgg visible to all

    // ---- mv1: h = relu(agg @ W1 + b1), lane = output col, 4-env ILP ----
    // chain order per env identical to round 1: d = 0..127 sequential
    float acc0 = b1v, acc1 = b1v, acc2 = b1v, acc3 = b1v;
    #pragma unroll 8
    for (int d4 = 0; d4 < DIN / 4; ++d4) {
        const float w0  = sW1[(4 * d4 + 0) * H1C + l];
        const float w1_ = sW1[(4 * d4 + 1) * H1C + l];
        const float w2_ = sW1[(4 * d4 + 2) * H1C + l];
        const float w3_ = sW1[(4 * d4 + 3) * H1C + l];
        const float4 a0 = *reinterpret_cast<const float4*>(&sAgg[le0 + 0][4 * d4]);
        const float4 a1 = *reinterpret_cast<const float4*>(&sAgg[le0 + 1][4 * d4]);
        const float4 a2 = *reinterpret_cast<const float4*>(&sAgg[le0 + 2][4 * d4]);
        const float4 a3 = *reinterpret_cast<const float4*>(&sAgg[le0 + 3][4 * d4]);
        acc0 = fmaf(a0.x, w0, acc0); acc0 = fmaf(a0.y, w1_, acc0);
        acc0 = fmaf(a0.z, w2_, acc0); acc0 = fmaf(a0.w, w3_, acc0);
        acc1 = fmaf(a1.x, w0, acc1); acc1 = fmaf(a1.y, w1_, acc1);
        acc1 = fmaf(a1.z, w2_, acc1); acc1 = fmaf(a1.w, w3_, acc1);
        acc2 = fmaf(a2.x, w0, acc2); acc2 = fmaf(a2.y, w1_, acc2);
        acc2 = fmaf(a2.z, w2_, acc2); acc2 = fmaf(a2.w, w3_, acc2);
        acc3 = fmaf(a3.x, w0, acc3); acc3 = fmaf(a3.y, w1_, acc3);
        acc3 = fmaf(a3.z, w2_, acc3); acc3 = fmaf(a3.w, w3_, acc3);
    }
    sH[le0 + 0][l] = fmaxf(acc0, 0.0f);
    sH[le0 + 1][l] = fmaxf(acc1, 0.0f);
    sH[le0 + 2][l] = fmaxf(acc2, 0.0f);
    sH[le0 + 3][l] = fmaxf(acc3, 0.0f);

    __syncthreads();   // sH visible

    // ---- mv2: p = h @ W2 + b2 ----
    acc0 = b2v; acc1 = b2v; acc2 = b2v; acc3 = b2v;
    #pragma unroll
    for (int k4 = 0; k4 < H1C / 4; ++k4) {
        const float w0  = sW2[(4 * k4 + 0) * DPC + l];
        const float w1_ = sW2[(4 * k4 + 1) * DPC + l];
        const float w2_ = sW2[(4 * k4 + 2) * DPC + l];
        const float w3_ = sW2[(4 * k4 + 3) * DPC + l];
        const float4 a0 = *reinterpret_cast<const float4*>(&sH[le0 + 0][4 * k4]);
        const float4 a1 = *reinterpret_cast<const float4*>(&sH[le0 + 1][4 * k4]);
        const float4 a2 = *reinterpret_cast<const float4*>(&sH[le0 + 2][4 * k4]);
        const float4 a3 = *reinterpret_cast<const float4*>(&sH[le0 + 3][4 * k4]);
        acc0 = fmaf(a0.x, w0, acc0); acc0 = fmaf(a0.y, w1_, acc0);
        acc0 = fmaf(a0.z, w2_, acc0); acc0 = fmaf(a0.w, w3_, acc0);
        acc1 = fmaf(a1.x, w0, acc1); acc1 = fmaf(a1.y, w1_, acc1);
        acc1 = fmaf(a1.z, w2_, acc1); acc1 = fmaf(a1.w, w3_, acc1);
        acc2 = fmaf(a2.x, w0, acc2); acc2 = fmaf(a2.y, w1_, acc2);
        acc2 = fmaf(a2.z, w2_, acc2); acc2 = fmaf(a2.w, w3_, acc2);
        acc3 = fmaf(a3.x, w0, acc3); acc3 = fmaf(a3.y, w1_, acc3);
        acc3 = fmaf(a3.z, w2_, acc3); acc3 = fmaf(a3.w, w3_, acc3);
    }
    sP[le0 + 0][l] = acc0;
    sP[le0 + 1][l] = acc1;
    sP[le0 + 2][l] = acc2;
    sP[le0 + 3][l] = acc3;

    __syncthreads();   // sP visible

    // ---- mv3: z = p @ Wfc (registers) ----
    float z0 = 0.f, z1 = 0.f, z2 = 0.f, z3 = 0.f;
    #pragma unroll
    for (int k4 = 0; k4 < DPC / 4; ++k4) {
        const float w0  = sWfc[(4 * k4 + 0) * DZC + l];
        const float w1_ = sWfc[(4 * k4 + 1) * DZC + l];
        const float w2_ = sWfc[(4 * k4 + 2) * DZC + l];
        const float w3_ = sWfc[(4 * k4 + 3) * DZC + l];
        const float4 a0 = *reinterpret_cast<const float4*>(&sP[le0 + 0][4 * k4]);
        const float4 a1 = *reinterpret_cast<const float4*>(&sP[le0 + 1][4 * k4]);
        const float4 a2 = *reinterpret_cast<const float4*>(&sP[le0 + 2][4 * k4]);
        const float4 a3 = *reinterpret_cast<const float4*>(&sP[le0 + 3][4 * k4]);
        z0 = fmaf(a0.x, w0, z0); z0 = fmaf(a0.y, w1_, z0);
        z0 = fmaf(a0.z, w2_, z0); z0 = fmaf(a0.w, w3_, z0);
        z1 = fmaf(a1.x, w0, z1); z1 = fmaf(a1.y, w1_, z1);
        z1 = fmaf(a1.z, w2_, z1); z1 = fmaf(a1.w, w3_, z1);
        z2 = fmaf(a2.x, w0, z2); z2 = fmaf(a2.y, w1_, z2);
        z2 = fmaf(a2.z, w2_, z2); z2 = fmaf(a2.w, w3_, z2);
        z3 = fmaf(a3.x, w0, z3); z3 = fmaf(a3.y, w1_, z3);
        z3 = fmaf(a3.z, w2_, z3); z3 = fmaf(a3.w, w3_, z3);
    }
    const float zz[WENV] = {z0, z1, z2, z3};

    // ---- per-env scalars (round-1 trees, bit-identical) ----
    float wgt[WENV], cc[WENV], Svv[WENV];
    #pragma unroll
    for (int ee = 0; ee < WENV; ++ee) {
        const int le = le0 + ee;
        float t0 = zz[ee] * (wa0 + wa1);
        float t1 = sP[le][l] * wvv;
        #pragma unroll
        for (int m = 32; m >= 1; m >>= 1) {
            t0 += __shfl_xor(t0, m);
            t1 += __shfl_xor(t1, m);
        }
        const float eV = (t0 > 0.0f) ? t0 : 0.01f * t0;   // leaky_relu slope 0.01
        wgt[ee] = 1.0f / (1.0f + expf(-eV));
        cc[ee]  = t1 + bvv;

        float q0 = (pv0[ee] - av0[ee]) * va;   // -> dv[l>>3]
        float q1 = (pv1[ee] - av1[ee]) * va;   // -> dv[8+(l>>3)]
        float fq = q0 + q1;
        float fp = (pv0[ee] + pv1[ee]) * va;
        #pragma unroll
        for (int m = 1; m <= 4; m <<= 1) {     // segmented 8-lane reduce (over a)
            q0 += __shfl_xor(q0, m);
            q1 += __shfl_xor(q1, m);
        }
        #pragma unroll
        for (int m = 32; m >= 1; m >>= 1) {    // full-wave reduces (round-1 tree)
            fq += __shfl_xor(fq, m);
            fp += __shfl_xor(fp, m);
        }
        Svv[ee] = fp - wgt[ee] * fq;

        if ((l & 7) == 0) {
            sDv[le][l >> 3]       = q0;
            sDv[le][8 + (l >> 3)] = q1;
        }
    }

    __syncthreads();   // sDv visible

    // ---- outputs: 16 distinct x per env, broadcast over d; w scalar ----
    const float invN = 1.0f / 16.0f;
    const int j0 = (4 * l) & 15;          // 0,4,8,12; j0..j0+3 never wrap
    #pragma unroll
    for (int ee = 0; ee < WENV; ++ee) {
        const int le = le0 + ee;
        float4 xo, wo;
        xo.x = fmaf(wgt[ee], sDv[le][j0 + 0], Svv[ee]) * invN + cc[ee];
        xo.y = fmaf(wgt[ee], sDv[le][j0 + 1], Svv[ee]) * invN + cc[ee];
        xo.z = fmaf(wgt[ee], sDv[le][j0 + 2], Svv[ee]) * invN + cc[ee];
        xo.w = fmaf(wgt[ee], sDv[le][j0 + 3], Svv[ee]) * invN + cc[ee];
        wo.x = wo.y = wo.z = wo.w = wgt[ee];

        const size_t base = (size_t)(e0 + ee) * (NN * NN) + 4 * l;
        *reinterpret_cast<float4*>(out_x + base) = xo;
        *reinterpret_cast<float4*>(out_w + base) = wo;
    }
}

extern "C" void kernel_launch(void* const* d_in, const int* in_sizes, int n_in,
                              void* d_out, int out_size, void* d_ws, size_t ws_size,
                              hipStream_t stream) {
    const float* obs      = (const float*)d_in[0];
    const float* policies = (const float*)d_in[1];
    const float* actions  = (const float*)d_in[2];
    const float* W1       = (const float*)d_in[3];
    const float* b1       = (const float*)d_in[4];
    const float* W2       = (const float*)d_in[5];
    const float* b2       = (const float*)d_in[6];
    const float* Wfc      = (const float*)d_in[7];
    const float* Wattn    = (const float*)d_in[8];
    const float* Wv       = (const float*)d_in[9];
    const float* bv       = (const float*)d_in[10];

    float* out_x = (float*)d_out;                    // [B*N*N] = 1048576
    float* out_w = out_x + (size_t)BB * NN * NN;     // second tuple element

    critic_kernel<<<BB / GENV, NTHR, 0, stream>>>(obs, policies, actions,
                                                  W1, b1, W2, b2, Wfc, Wattn, Wv, bv,
                                                  out_x, out_w);
}